// Round 2
// baseline (2203.405 us; speedup 1.0000x reference)
//
#include <hip/hip_runtime.h>
#include <hip/hip_bf16.h>

typedef _Float16 half8 __attribute__((ext_vector_type(8)));
typedef float floatx4 __attribute__((ext_vector_type(4)));

#define N_NODES 10000
#define F_NODE  128
#define C_GCN   64
#define N_EDGES 160000
#define T_SEQ   96
#define S_SEQ   32
#define HID     128
#define M_BLK   40          // nodes per block (250 blocks exactly)
#define MT      3           // 3 m-tiles of 16 -> 48 rows (40 real + 8 zero pad)
#define SEQ_STRIDE 104      // 96 + 8 f16 pad (208 B, 16B multiple)
#define H_STRIDE   136      // 128 + 8 f16 pad (272 B, 16B multiple)

// ---------------- fast activations (f32) ----------------
__device__ __forceinline__ float sigm_f(float x) {
    float e = exp2f(x * -1.44269504088896f);
    return 1.0f / (1.0f + e);
}
__device__ __forceinline__ float tanh_f(float x) {
    float e = exp2f(x * 2.88539008177793f);
    return 1.0f - 2.0f / (e + 1.0f);
}

// ---------------- GCN kernels (all fp32, tiny) ----------------
__global__ void k_gcn_xw(const float* __restrict__ nf, const float* __restrict__ w,
                         float* __restrict__ xw) {
    int tid = blockIdx.x * 256 + threadIdx.x;
    int n = tid >> 6, c = tid & 63;
    if (n >= N_NODES) return;
    float s = 0.f;
    #pragma unroll 8
    for (int k = 0; k < F_NODE; ++k) s = fmaf(nf[n * F_NODE + k], w[k * C_GCN + c], s);
    xw[n * C_GCN + c] = s;
}

__global__ void k_deg_init(float* __restrict__ deg) {
    int i = blockIdx.x * 256 + threadIdx.x;
    if (i < N_NODES) deg[i] = 1.0f;   // self loop
}

__global__ void k_deg_count(const int* __restrict__ ei, float* __restrict__ deg) {
    int e = blockIdx.x * 256 + threadIdx.x;
    if (e < N_EDGES) atomicAdd(&deg[ei[N_EDGES + e]], 1.0f);
}

__global__ void k_dinv(const float* __restrict__ deg, float* __restrict__ dinv) {
    int i = blockIdx.x * 256 + threadIdx.x;
    if (i < N_NODES) dinv[i] = rsqrtf(deg[i]);
}

__global__ void k_gcn_self(const float* __restrict__ xw, const float* __restrict__ dinv,
                           const float* __restrict__ gb, float* __restrict__ gout) {
    int tid = blockIdx.x * 256 + threadIdx.x;
    int n = tid >> 6, c = tid & 63;
    if (n >= N_NODES) return;
    float di = dinv[n];
    gout[tid] = xw[tid] * di * di + gb[c];
}

__global__ void k_gcn_scatter(const int* __restrict__ ei, const float* __restrict__ xw,
                              const float* __restrict__ dinv, float* __restrict__ gout) {
    int e = blockIdx.x * 4 + (threadIdx.x >> 6);
    int c = threadIdx.x & 63;
    if (e >= N_EDGES) return;
    int r  = ei[e];
    int cl = ei[N_EDGES + e];
    float nm = dinv[r] * dinv[cl];
    atomicAdd(&gout[cl * C_GCN + c], xw[r * C_GCN + c] * nm);
}

// ---------------- weight packing: f32 [512][K] -> f16 MFMA-frag-linear ----------------
// frag id f = nt*KT + kt; per frag 64 lanes x 8 f16.
// lane holds B[k = kt*32 + (lane>>4)*8 + j][n = nt*16 + (lane&15)] = W[n][k]
__global__ void k_pack(const float* __restrict__ w_ih0, const float* __restrict__ w_hh0,
                       const float* __restrict__ w_ih1, const float* __restrict__ w_hh1,
                       half8* __restrict__ pW) {
    int tid = blockIdx.x * 256 + threadIdx.x;
    if (tid >= 480 * 64) return;
    int fid = tid >> 6, lane = tid & 63;
    const float* src; int KT, fbase;
    if (fid < 96)       { src = w_ih0; KT = 3; fbase = 0;   }
    else if (fid < 224) { src = w_hh0; KT = 4; fbase = 96;  }
    else if (fid < 352) { src = w_ih1; KT = 4; fbase = 224; }
    else                { src = w_hh1; KT = 4; fbase = 352; }
    int f  = fid - fbase;
    int nt = f / KT, kt = f % KT;
    int K  = KT * 32;
    int g  = nt * 16 + (lane & 15);
    int k0 = kt * 32 + (lane >> 4) * 8;
    half8 v;
    #pragma unroll
    for (int j = 0; j < 8; ++j) v[j] = (_Float16)src[g * K + k0 + j];
    pW[tid] = v;
}

__global__ void k_bsum(const float* __restrict__ bi0, const float* __restrict__ bh0,
                       const float* __restrict__ bi1, const float* __restrict__ bh1,
                       float* __restrict__ bs) {
    int i = blockIdx.x * 256 + threadIdx.x;
    if (i < 512)       bs[i] = bi0[i] + bh0[i];
    else if (i < 1024) bs[i] = bi1[i - 512] + bh1[i - 512];
}

// ---------------- fused 2-layer LSTM + FC ----------------
template<int KT>
__device__ __forceinline__ void gemm_tiles(floatx4 acc[4][MT], const half8* __restrict__ pack,
                                           const _Float16* A, int strideA, int lane, int wid) {
    const int l15 = lane & 15, quad = lane >> 4;
    #pragma unroll
    for (int kt = 0; kt < KT; ++kt) {
        half8 a[MT];
        #pragma unroll
        for (int mt = 0; mt < MT; ++mt)
            a[mt] = *(const half8*)(A + (mt * 16 + l15) * strideA + kt * 32 + quad * 8);
        #pragma unroll
        for (int g = 0; g < 4; ++g) {
            half8 b = pack[(size_t)((8 * g + wid) * KT + kt) * 64 + lane];
            #pragma unroll
            for (int mt = 0; mt < MT; ++mt)
                acc[g][mt] = __builtin_amdgcn_mfma_f32_16x16x32_f16(a[mt], b, acc[g][mt], 0, 0, 0);
        }
    }
}

__device__ __forceinline__ void epilogue(floatx4 acc[4][MT], const float bias[4],
                                         float c[MT][4], _Float16* Hnext,
                                         int quad, int ch) {
    #pragma unroll
    for (int mt = 0; mt < MT; ++mt) {
        #pragma unroll
        for (int r = 0; r < 4; ++r) {
            float gi = acc[0][mt][r] + bias[0];
            float gf = acc[1][mt][r] + bias[1];
            float gg = acc[2][mt][r] + bias[2];
            float go = acc[3][mt][r] + bias[3];
            float cn = sigm_f(gf) * c[mt][r] + sigm_f(gi) * tanh_f(gg);
            c[mt][r] = cn;
            float h = sigm_f(go) * tanh_f(cn);
            Hnext[(mt * 16 + quad * 4 + r) * H_STRIDE + ch] = (_Float16)h;
        }
    }
}

__global__ __launch_bounds__(512, 2) void k_lstm(
    const float* __restrict__ seq, const float* __restrict__ gcn,
    const half8* __restrict__ pW, const float* __restrict__ bsum,
    const float* __restrict__ fcw, const float* __restrict__ fcb,
    float* __restrict__ out) {

    __shared__ __align__(16) _Float16 sSeq[48 * SEQ_STRIDE];
    __shared__ __align__(16) _Float16 sH0[2][48 * H_STRIDE];
    __shared__ __align__(16) _Float16 sH1[2][48 * H_STRIDE];

    const int tid  = threadIdx.x;
    const int wid  = tid >> 6;
    const int lane = tid & 63;
    const int l15  = lane & 15;
    const int quad = lane >> 4;
    const int node0 = blockIdx.x * M_BLK;
    const int ch = wid * 16 + l15;      // this wave's hidden channel for epilogue

    // zero LDS (pad rows 40..47 of A stay zero forever)
    for (int i = tid; i < 48 * SEQ_STRIDE; i += 512) sSeq[i] = (_Float16)0.f;
    for (int i = tid; i < 48 * H_STRIDE; i += 512) {
        sH0[0][i] = (_Float16)0.f; sH0[1][i] = (_Float16)0.f;
        sH1[0][i] = (_Float16)0.f; sH1[1][i] = (_Float16)0.f;
    }

    // biases (i,f,g,o for this lane's channel)
    float bias0[4], bias1[4];
    #pragma unroll
    for (int g = 0; g < 4; ++g) {
        bias0[g] = bsum[g * 128 + ch];
        bias1[g] = bsum[512 + g * 128 + ch];
    }

    float c0[MT][4] = {{0}}, c1[MT][4] = {{0}};

    const half8* pIH0 = pW;
    const half8* pHH0 = pW + 96  * 64;
    const half8* pIH1 = pW + 224 * 64;
    const half8* pHH1 = pW + 352 * 64;

    __syncthreads();  // zeros visible before staging writes mix in

    // stage constant gcn columns (32..95) and seq t=0 (cols 0..31)
    for (int i = tid; i < M_BLK * (C_GCN / 2); i += 512) {
        int r = i >> 5, cp = (i & 31) * 2;
        float2 v = *(const float2*)(gcn + (size_t)(node0 + r) * C_GCN + cp);
        sSeq[r * SEQ_STRIDE + S_SEQ + cp]     = (_Float16)v.x;
        sSeq[r * SEQ_STRIDE + S_SEQ + cp + 1] = (_Float16)v.y;
    }
    for (int i = tid; i < M_BLK * (S_SEQ / 2); i += 512) {
        int r = i >> 4, cp = (i & 15) * 2;
        float2 v = *(const float2*)(seq + ((size_t)(node0 + r) * T_SEQ) * S_SEQ + cp);
        sSeq[r * SEQ_STRIDE + cp]     = (_Float16)v.x;
        sSeq[r * SEQ_STRIDE + cp + 1] = (_Float16)v.y;
    }
    __syncthreads();

    floatx4 acc[4][MT];

    for (int t = 0; t < T_SEQ; ++t) {
        const int cur = t & 1, nxt = cur ^ 1;

        // ---- phase A: layer 0 ----
        #pragma unroll
        for (int g = 0; g < 4; ++g)
            #pragma unroll
            for (int mt = 0; mt < MT; ++mt)
                acc[g][mt] = (floatx4){0.f, 0.f, 0.f, 0.f};
        gemm_tiles<3>(acc, pIH0, sSeq, SEQ_STRIDE, lane, wid);
        gemm_tiles<4>(acc, pHH0, &sH0[cur][0], H_STRIDE, lane, wid);
        epilogue(acc, bias0, c0, &sH0[nxt][0], quad, ch);
        __syncthreads();  // h0(t) visible for layer 1

        // ---- phase B: layer 1 (+ stage seq t+1; phase A readers are done) ----
        if (t + 1 < T_SEQ) {
            for (int i = tid; i < M_BLK * (S_SEQ / 2); i += 512) {
                int r = i >> 4, cp = (i & 15) * 2;
                float2 v = *(const float2*)(seq + ((size_t)(node0 + r) * T_SEQ + (t + 1)) * S_SEQ + cp);
                sSeq[r * SEQ_STRIDE + cp]     = (_Float16)v.x;
                sSeq[r * SEQ_STRIDE + cp + 1] = (_Float16)v.y;
            }
        }
        #pragma unroll
        for (int g = 0; g < 4; ++g)
            #pragma unroll
            for (int mt = 0; mt < MT; ++mt)
                acc[g][mt] = (floatx4){0.f, 0.f, 0.f, 0.f};
        gemm_tiles<4>(acc, pIH1, &sH0[nxt][0], H_STRIDE, lane, wid);
        gemm_tiles<4>(acc, pHH1, &sH1[cur][0], H_STRIDE, lane, wid);
        epilogue(acc, bias1, c1, &sH1[nxt][0], quad, ch);
        __syncthreads();  // h1(t) + seq(t+1) visible
    }

    // final h1 lives in buffer (T_SEQ & 1) == 0
    if (tid < M_BLK) {
        const _Float16* h1 = &sH1[0][tid * H_STRIDE];
        float s = fcb[0];
        #pragma unroll 16
        for (int k = 0; k < HID; ++k) s = fmaf((float)h1[k], fcw[k], s);
        out[node0 + tid] = s;
    }
}

// ---------------- launch ----------------
extern "C" void kernel_launch(void* const* d_in, const int* in_sizes, int n_in,
                              void* d_out, int out_size, void* d_ws, size_t ws_size,
                              hipStream_t stream) {
    const float* seq   = (const float*)d_in[0];
    const int*   ei    = (const int*)d_in[1];     // int64 in reference -> int32 on device
    // d_in[2] edge_attr: unused by reference
    const float* nf    = (const float*)d_in[3];
    // d_in[4] node_indices: unused by reference
    const float* gcn_w = (const float*)d_in[5];
    const float* gcn_b = (const float*)d_in[6];
    const float* w_ih0 = (const float*)d_in[7];
    const float* w_hh0 = (const float*)d_in[8];
    const float* b_ih0 = (const float*)d_in[9];
    const float* b_hh0 = (const float*)d_in[10];
    const float* w_ih1 = (const float*)d_in[11];
    const float* w_hh1 = (const float*)d_in[12];
    const float* b_ih1 = (const float*)d_in[13];
    const float* b_hh1 = (const float*)d_in[14];
    const float* fc_w  = (const float*)d_in[15];
    const float* fc_b  = (const float*)d_in[16];
    float* out = (float*)d_out;

    char* ws = (char*)d_ws;
    float* xw   = (float*)(ws);                    // 2,560,000 B
    float* gout = (float*)(ws + 2621440);          // 2,560,000 B
    float* deg  = (float*)(ws + 5242880);          // 40,000 B
    float* dinv = (float*)(ws + 5283840);          // 40,000 B
    float* bsum = (float*)(ws + 5324800);          // 4,096 B
    half8* pW   = (half8*)(ws + 5328896);          // 491,520 B  (16B aligned)

    // GCN (fp32 exact)
    k_gcn_xw     <<<2500,  256, 0, stream>>>(nf, gcn_w, xw);
    k_deg_init   <<<40,    256, 0, stream>>>(deg);
    k_deg_count  <<<625,   256, 0, stream>>>(ei, deg);
    k_dinv       <<<40,    256, 0, stream>>>(deg, dinv);
    k_gcn_self   <<<2500,  256, 0, stream>>>(xw, dinv, gcn_b, gout);
    k_gcn_scatter<<<40000, 256, 0, stream>>>(ei, xw, dinv, gout);

    // weight prep
    k_pack<<<120, 256, 0, stream>>>(w_ih0, w_hh0, w_ih1, w_hh1, pW);
    k_bsum<<<4,   256, 0, stream>>>(b_ih0, b_hh0, b_ih1, b_hh1, bsum);

    // fused 2-layer LSTM + FC
    k_lstm<<<250, 512, 0, stream>>>(seq, gout, pW, bsum, fc_w, fc_b, out);
}